// Round 2
// baseline (396.194 us; speedup 1.0000x reference)
//
#include <hip/hip_runtime.h>
#include <math.h>

#define BSZ 4
#define NE 40
#define DM 128
#define DR 128
#define NE2 80
#define NROW_BI (NE*NE)       // 1600 rows per (b,i)
#define NBIJ (BSZ*NE*NE)      // 6400
#define BI_CNT (BSZ*NE)       // 160

__device__ __forceinline__ float gelu_exact(float x) {
    return 0.5f * x * (1.0f + erff(x * 0.70710678118654752f));
}

// ---------------------------------------------------------------------------
// K1: ht_proj[bi,j,:] = ht[bi,j,:] @ Wc_ht + b_comb   (6400 rows x 128)
// 400 blocks x 256 threads, 16 rows/block. W staged in LDS (64KB).
// thread: tc = t&15 -> cols {4tc..4tc+3, 64+4tc..}, rs = t>>4 -> row slot.
// ---------------------------------------------------------------------------
__global__ __launch_bounds__(256, 2)
void k1_htproj(const float* __restrict__ ht, const float* __restrict__ Wcomb,
               const float* __restrict__ bcomb, float* __restrict__ htp) {
    __shared__ float WL[DM*DM];
    __shared__ float rowbuf[16][132];   // pad 132: broadcast reads hit 4 banks
    const int t = threadIdx.x;
    const int row0 = blockIdx.x * 16;

    const float4* Wsrc4 = (const float4*)Wcomb;   // first 128 rows = Wc_ht
    float4* WL4s = (float4*)WL;
    #pragma unroll
    for (int it = 0; it < 16; ++it) WL4s[it*256 + t] = Wsrc4[it*256 + t];

    const float4* ht4 = (const float4*)ht;
    #pragma unroll
    for (int it = 0; it < 2; ++it) {
        int f4 = it*256 + t; int r = f4 >> 5, q = f4 & 31;
        *(float4*)&rowbuf[r][q*4] = ht4[(size_t)(row0 + r)*32 + q];
    }
    __syncthreads();

    const int tc = t & 15, rs = t >> 4;
    const float4* bc4 = (const float4*)bcomb;
    float4 c0 = bc4[tc], c1 = bc4[16 + tc];
    float acc[8] = {c0.x,c0.y,c0.z,c0.w,c1.x,c1.y,c1.z,c1.w};
    const float4* WL4 = (const float4*)WL;
    #pragma unroll 8
    for (int d = 0; d < DM; ++d) {
        float a = rowbuf[rs][d];
        float4 b0 = WL4[d*32 + tc], b1 = WL4[d*32 + 16 + tc];
        acc[0] = fmaf(a, b0.x, acc[0]); acc[1] = fmaf(a, b0.y, acc[1]);
        acc[2] = fmaf(a, b0.z, acc[2]); acc[3] = fmaf(a, b0.w, acc[3]);
        acc[4] = fmaf(a, b1.x, acc[4]); acc[5] = fmaf(a, b1.y, acc[5]);
        acc[6] = fmaf(a, b1.z, acc[6]); acc[7] = fmaf(a, b1.w, acc[7]);
    }
    float4* o4 = (float4*)htp;
    float4 o0 = {acc[0],acc[1],acc[2],acc[3]}, o1 = {acc[4],acc[5],acc[6],acc[7]};
    o4[(size_t)(row0 + rs)*32 + tc]      = o0;
    o4[(size_t)(row0 + rs)*32 + 16 + tc] = o1;
}

// ---------------------------------------------------------------------------
// K2: fused  fp = factor_row @ Wc_f ;  e1 = wv.gelu(fp + htp[bi,j]) ;
//            e2 = wv.gelu(fp + htp[bi,k])  -> energy scatter (+mask).
// 2000 blocks x 256 threads. M=128 rows/block, K=128 in 2 chunks of 64.
// LDS: As[128][65] (33280B, pad-65 keeps a-frag broadcasts on 4 banks) +
//      Ws[64][128] (32768B) = 66048B -> 2 blocks/CU.
// Thread tile 8x8: rows tr*8..+7 (tr=t>>4), cols {4tc..+3, 64+4tc..+3}.
// ---------------------------------------------------------------------------
__global__ __launch_bounds__(256, 2)
void k2_energy(const float* __restrict__ factor, const float* __restrict__ Wcomb,
               const float* __restrict__ wv, const float* __restrict__ htp,
               const int* __restrict__ entn, float* __restrict__ energy) {
    __shared__ float AsL[128*65];
    __shared__ float Ws[64*128];
    const int t = threadIdx.x;
    const int tc = t & 15, tr = t >> 4;
    const int row0 = blockIdx.x * 128;

    float acc[8][8];
    #pragma unroll
    for (int i = 0; i < 8; ++i)
        #pragma unroll
        for (int jj = 0; jj < 8; ++jj) acc[i][jj] = 0.0f;

    const float4* Wf4 = (const float4*)(Wcomb + (size_t)DR*DM);  // Wc_f
    const float*  ap  = AsL + tr*8*65;
    const float4* Ws4 = (const float4*)Ws;

    for (int c = 0; c < 2; ++c) {
        if (c) __syncthreads();
        // stage A chunk: rows row0..row0+127, d in [c*64, c*64+64)
        #pragma unroll
        for (int it = 0; it < 8; ++it) {
            int r = it*16 + tr;
            float4 v = *(const float4*)(factor + (size_t)(row0 + r)*128 + c*64 + tc*4);
            float* dst = &AsL[r*65 + tc*4];
            dst[0] = v.x; dst[1] = v.y; dst[2] = v.z; dst[3] = v.w;
        }
        // stage W chunk: 64x128 floats = 2048 float4
        float4* Ws4s = (float4*)Ws;
        #pragma unroll
        for (int it = 0; it < 8; ++it) {
            int f4 = it*256 + t;
            Ws4s[f4] = Wf4[(size_t)c*64*32 + f4];
        }
        __syncthreads();

        #pragma unroll 4
        for (int dl = 0; dl < 64; ++dl) {
            float4 b0 = Ws4[dl*32 + tc];
            float4 b1 = Ws4[dl*32 + 16 + tc];
            float b[8] = {b0.x,b0.y,b0.z,b0.w,b1.x,b1.y,b1.z,b1.w};
            #pragma unroll
            for (int ri = 0; ri < 8; ++ri) {
                float a = ap[ri*65 + dl];
                #pragma unroll
                for (int jj = 0; jj < 8; ++jj)
                    acc[ri][jj] = fmaf(a, b[jj], acc[ri][jj]);
            }
        }
    }

    // energy phase
    const float4* wv4 = (const float4*)wv;
    float4 wa = wv4[tc], wb = wv4[16 + tc];
    float wvv[8] = {wa.x,wa.y,wa.z,wa.w,wb.x,wb.y,wb.z,wb.w};
    const int e0 = entn[0], e1n = entn[1], e2n = entn[2], e3 = entn[3];

    #pragma unroll
    for (int ri = 0; ri < 8; ++ri) {
        int row_g = row0 + tr*8 + ri;
        int bi  = row_g / NROW_BI;
        int rem = row_g - bi*NROW_BI;
        int j = rem / NE;
        int k = rem - j*NE;
        const float4* h1 = (const float4*)(htp + (size_t)(bi*NE + j)*DM);
        const float4* h2 = (const float4*)(htp + (size_t)(bi*NE + k)*DM);
        float4 h1a = h1[tc], h1b = h1[16 + tc];
        float4 h2a = h2[tc], h2b = h2[16 + tc];
        float hv1[8] = {h1a.x,h1a.y,h1a.z,h1a.w,h1b.x,h1b.y,h1b.z,h1b.w};
        float hv2[8] = {h2a.x,h2a.y,h2a.z,h2a.w,h2b.x,h2b.y,h2b.z,h2b.w};
        float p1 = 0.0f, p2 = 0.0f;
        #pragma unroll
        for (int jj = 0; jj < 8; ++jj) {
            p1 = fmaf(wvv[jj], gelu_exact(acc[ri][jj] + hv1[jj]), p1);
            p2 = fmaf(wvv[jj], gelu_exact(acc[ri][jj] + hv2[jj]), p2);
        }
        p1 += __shfl_xor(p1, 1); p2 += __shfl_xor(p2, 1);
        p1 += __shfl_xor(p1, 2); p2 += __shfl_xor(p2, 2);
        p1 += __shfl_xor(p1, 4); p2 += __shfl_xor(p2, 4);
        p1 += __shfl_xor(p1, 8); p2 += __shfl_xor(p2, 8);
        if (tc == 0) {
            int b = bi / NE, i = bi - b*NE;
            int en = (b == 0) ? e0 : (b == 1) ? e1n : (b == 2) ? e2n : e3;
            bool msk = (j == k) || !((i < en) && (j < en) && (k < en));
            float v1 = msk ? -10000.0f : p1;
            float v2 = msk ? -10000.0f : p2;
            energy[(size_t)(bi*NE + j)*NE2 + k]       = v1;
            energy[(size_t)(bi*NE + k)*NE2 + NE + j]  = v2;
        }
    }
}

// ---------------------------------------------------------------------------
// K3: per (b,i,j): softmax over 80 energies, then
//     av = sum_k a[k]*factor[bi,j,k,:] + sum_q a[40+q]*factor[bi,q,j,:].
// 6400 blocks x 64 threads (1 wave). j-major remap: bi = gid%160 -> blocks
// sharing a (b,i) slice keep bi%8 constant -> same XCD L2 for transposed reads.
// ---------------------------------------------------------------------------
__global__ __launch_bounds__(64)
void k3_attn_av(const float* __restrict__ energy, const float* __restrict__ factor,
                float* __restrict__ av) {
    __shared__ float att[NE2];
    const int l = threadIdx.x;
    const int gid = blockIdx.x;
    const int bi = gid % BI_CNT;
    const int j  = gid / BI_CNT;

    const float* eb = energy + (size_t)(bi*NE + j)*NE2;
    float ea = eb[l];
    float ebv = (l < 16) ? eb[64 + l] : -INFINITY;
    float m = fmaxf(ea, ebv);
    m = fmaxf(m, __shfl_xor(m, 1));  m = fmaxf(m, __shfl_xor(m, 2));
    m = fmaxf(m, __shfl_xor(m, 4));  m = fmaxf(m, __shfl_xor(m, 8));
    m = fmaxf(m, __shfl_xor(m, 16)); m = fmaxf(m, __shfl_xor(m, 32));
    float x1 = expf(ea - m);
    float x2 = (l < 16) ? expf(ebv - m) : 0.0f;
    float s = x1 + x2;
    s += __shfl_xor(s, 1);  s += __shfl_xor(s, 2);
    s += __shfl_xor(s, 4);  s += __shfl_xor(s, 8);
    s += __shfl_xor(s, 16); s += __shfl_xor(s, 32);
    att[l] = x1 / s;
    if (l < 16) att[64 + l] = x2 / s;
    __syncthreads();

    float av0 = 0.0f, av1 = 0.0f;
    const float* f1 = factor + (size_t)(bi*NROW_BI + j*NE)*128;
    #pragma unroll 8
    for (int k = 0; k < NE; ++k) {
        float w = att[k];
        av0 = fmaf(w, f1[k*128 + l],      av0);
        av1 = fmaf(w, f1[k*128 + 64 + l], av1);
    }
    const float* f2 = factor + (size_t)(bi*NROW_BI + j)*128;
    #pragma unroll 8
    for (int q = 0; q < NE; ++q) {
        float w = att[NE + q];
        av0 = fmaf(w, f2[(size_t)q*NE*128 + l],      av0);
        av1 = fmaf(w, f2[(size_t)q*NE*128 + 64 + l], av1);
    }
    float* o = av + (size_t)(bi*NE + j)*128;
    o[l] = av0; o[64 + l] = av1;
}

// ---------------------------------------------------------------------------
// K4: out = LN(av @ W_fc + b_fc + ht) * scale + bias.  Two-pass variance
// (matches reference mean((x-mu)^2)). 400 blocks x 256 thr, 16 rows/block.
// ---------------------------------------------------------------------------
__global__ __launch_bounds__(256, 2)
void k4_out(const float* __restrict__ av, const float* __restrict__ Wfc,
            const float* __restrict__ bfc, const float* __restrict__ ht,
            const float* __restrict__ lns, const float* __restrict__ lnb,
            float* __restrict__ out) {
    __shared__ float WL[DM*DR];
    __shared__ float rowbuf[16][132];
    const int t = threadIdx.x;
    const int row0 = blockIdx.x * 16;

    const float4* W4 = (const float4*)Wfc;
    float4* WL4s = (float4*)WL;
    #pragma unroll
    for (int it = 0; it < 16; ++it) WL4s[it*256 + t] = W4[it*256 + t];
    const float4* av4 = (const float4*)av;
    #pragma unroll
    for (int it = 0; it < 2; ++it) {
        int f4 = it*256 + t; int r = f4 >> 5, q = f4 & 31;
        *(float4*)&rowbuf[r][q*4] = av4[(size_t)(row0 + r)*32 + q];
    }
    __syncthreads();

    const int tc = t & 15, rs = t >> 4;
    const int row = row0 + rs;
    const float4* bf4 = (const float4*)bfc;
    float4 c0 = bf4[tc], c1 = bf4[16 + tc];
    float acc[8] = {c0.x,c0.y,c0.z,c0.w,c1.x,c1.y,c1.z,c1.w};
    const float4* WL4 = (const float4*)WL;
    #pragma unroll 8
    for (int d = 0; d < DM; ++d) {
        float a = rowbuf[rs][d];
        float4 b0 = WL4[d*32 + tc], b1 = WL4[d*32 + 16 + tc];
        acc[0] = fmaf(a, b0.x, acc[0]); acc[1] = fmaf(a, b0.y, acc[1]);
        acc[2] = fmaf(a, b0.z, acc[2]); acc[3] = fmaf(a, b0.w, acc[3]);
        acc[4] = fmaf(a, b1.x, acc[4]); acc[5] = fmaf(a, b1.y, acc[5]);
        acc[6] = fmaf(a, b1.z, acc[6]); acc[7] = fmaf(a, b1.w, acc[7]);
    }
    const float4* ht4 = (const float4*)ht;
    float4 ha = ht4[(size_t)row*32 + tc], hb = ht4[(size_t)row*32 + 16 + tc];
    float o[8];
    o[0] = acc[0] + ha.x; o[1] = acc[1] + ha.y; o[2] = acc[2] + ha.z; o[3] = acc[3] + ha.w;
    o[4] = acc[4] + hb.x; o[5] = acc[5] + hb.y; o[6] = acc[6] + hb.z; o[7] = acc[7] + hb.w;

    float s1 = o[0]+o[1]+o[2]+o[3]+o[4]+o[5]+o[6]+o[7];
    s1 += __shfl_xor(s1, 1); s1 += __shfl_xor(s1, 2);
    s1 += __shfl_xor(s1, 4); s1 += __shfl_xor(s1, 8);
    float mu = s1 * (1.0f/128.0f);
    float s2 = 0.0f;
    #pragma unroll
    for (int jj = 0; jj < 8; ++jj) { float d = o[jj] - mu; s2 = fmaf(d, d, s2); }
    s2 += __shfl_xor(s2, 1); s2 += __shfl_xor(s2, 2);
    s2 += __shfl_xor(s2, 4); s2 += __shfl_xor(s2, 8);
    float var = s2 * (1.0f/128.0f);
    float rstd = 1.0f / sqrtf(var + 1e-6f);

    const float4* sc4 = (const float4*)lns;
    const float4* bs4 = (const float4*)lnb;
    float4 sa = sc4[tc], sb = sc4[16 + tc];
    float4 ba = bs4[tc], bb = bs4[16 + tc];
    float4 r0, r1;
    r0.x = (o[0]-mu)*rstd*sa.x + ba.x; r0.y = (o[1]-mu)*rstd*sa.y + ba.y;
    r0.z = (o[2]-mu)*rstd*sa.z + ba.z; r0.w = (o[3]-mu)*rstd*sa.w + ba.w;
    r1.x = (o[4]-mu)*rstd*sb.x + bb.x; r1.y = (o[5]-mu)*rstd*sb.y + bb.y;
    r1.z = (o[6]-mu)*rstd*sb.z + bb.z; r1.w = (o[7]-mu)*rstd*sb.w + bb.w;
    float4* o4 = (float4*)out;
    o4[(size_t)row*32 + tc]      = r0;
    o4[(size_t)row*32 + 16 + tc] = r1;
}

// ---------------------------------------------------------------------------
extern "C" void kernel_launch(void* const* d_in, const int* in_sizes, int n_in,
                              void* d_out, int out_size, void* d_ws, size_t ws_size,
                              hipStream_t stream) {
    const float* ht     = (const float*)d_in[0];
    const float* factor = (const float*)d_in[1];
    const int*   entn   = (const int*)  d_in[2];
    const float* Wcomb  = (const float*)d_in[3];
    const float* bcomb  = (const float*)d_in[4];
    const float* wv     = (const float*)d_in[5];
    const float* Wfc    = (const float*)d_in[6];
    const float* bfc    = (const float*)d_in[7];
    const float* lns    = (const float*)d_in[8];
    const float* lnb    = (const float*)d_in[9];
    float* out = (float*)d_out;

    char* ws = (char*)d_ws;
    float* htp    = (float*)(ws);                       // 6400*128*4   = 3,276,800 B
    float* energy = (float*)(ws + 3276800);             // 6400*80*4    = 2,048,000 B
    float* av     = (float*)(ws + 3276800 + 2048000);   // 6400*128*4   = 3,276,800 B

    k1_htproj<<<dim3(NBIJ/16), dim3(256), 0, stream>>>(ht, Wcomb, bcomb, htp);
    k2_energy<<<dim3(2000),    dim3(256), 0, stream>>>(factor, Wcomb, wv, htp, entn, energy);
    k3_attn_av<<<dim3(NBIJ),   dim3(64),  0, stream>>>(energy, factor, av);
    k4_out<<<dim3(NBIJ/16),    dim3(256), 0, stream>>>(av, Wfc, bfc, ht, lns, lnb, out);
}